// Round 18
// baseline (153.952 us; speedup 1.0000x reference)
//
#include <hip/hip_runtime.h>

// Trilinear feature-grid interpolation, v13: res-coalesced gather + unbin.
// grid layout: [R][R][R][3] = [z][y][x][c], R=256, fp32 (192 MB).
//
// Round-17 analysis: all eight staged-gather variants pay ~7.8K cy per
// 27.6KB z-step; the common poison is the scattered 12B out-stores inside
// the vmcnt-drained region (stores count toward vmcnt; each step's barrier
// waits for ~256 random-line L2-miss stores, ~500-900cy each class).
// v13: gather writes results COALESCED into res[slot] (float4 {o,idx},
// slot-parallel to binned) -> drains are cheap; a barrier-free streaming
// k_unbin (round-2 structure, which sustained 3.2 TB/s) scatters res->out.

#define NB     8192
#define CAP    512u
#define GBLK   1024
#define LAYERF4 1728              // float4 per layer (9 rows x 192 f4, contiguous)
#define LAYERF  6912              // floats per layer (27648 B)
#define GRIDF4  12582912          // total float4 in grid

// ws layout: binned[8192*512] f4 = 64MB @0; res[8192*512] f4 = 64MB; cur[8192]
#define RES_OFF   67108864u
#define CUR_OFF   134217728u
#define NEEDED    (134217728u + 32768u)

typedef float f4v __attribute__((ext_vector_type(4)));
typedef float f2v __attribute__((ext_vector_type(2)));
typedef f4v f4u __attribute__((aligned(8)));
typedef f2v f2u __attribute__((aligned(8)));

__device__ __forceinline__ void cell_of(float p, int& l, float& t) {
    float s = p * 255.0f;
    int v = (int)floorf(s);
    v = v < 0 ? 0 : (v > 254 ? 254 : v);
    l = v;
    t = s - (float)v;
}

// fine bin: K = zl*32 + (yl>>3)  (full x, 8 y-cells, 1 z-cell)
__device__ __forceinline__ int fine_bin3(float px, float py, float pz) {
    int xl, yl, zl; float tx, ty, tz;
    cell_of(px, xl, tx);
    cell_of(py, yl, ty);
    cell_of(pz, zl, tz);
    return (zl << 5) | (yl >> 3);
}

__device__ __forceinline__ void direct_lerp(const float* __restrict__ grid,
                                            float* __restrict__ out, int i,
                                            int xl, int yl, int zl,
                                            float tx, float ty, float tz) {
    int b00 = (zl * 65536 + yl * 256 + xl) * 3;
    int b01 = b00 + 768, b10 = b00 + 196608, b11 = b10 + 768;
    float s00[6], s01[6], s10[6], s11[6];
#pragma unroll
    for (int k = 0; k < 6; ++k) s00[k] = grid[b00 + k];
#pragma unroll
    for (int k = 0; k < 6; ++k) s01[k] = grid[b01 + k];
#pragma unroll
    for (int k = 0; k < 6; ++k) s10[k] = grid[b10 + k];
#pragma unroll
    for (int k = 0; k < 6; ++k) s11[k] = grid[b11 + k];
#pragma unroll
    for (int c = 0; c < 3; ++c) {
        float c00 = s00[c] * (1.0f - tx) + s00[c + 3] * tx;
        float c01 = s01[c] * (1.0f - tx) + s01[c + 3] * tx;
        float c10 = s10[c] * (1.0f - tx) + s10[c + 3] * tx;
        float c11 = s11[c] * (1.0f - tx) + s11[c + 3] * tx;
        float c0 = c00 * (1.0f - ty) + c01 * ty;
        float c1 = c10 * (1.0f - ty) + c11 * ty;
        out[3 * i + c] = c0 * (1.0f - tz) + c1 * tz;
    }
}

// ---------------- pass 0: init cursors to region bases ----------------
__global__ __launch_bounds__(1024) void k_init(unsigned* __restrict__ cur) {
    int i = blockIdx.x * 1024 + threadIdx.x;
    if (i < NB) cur[i] = (unsigned)i * CAP;
}

// ---------------- pass 1: block-aggregated scatter (2 pts/thread) ----------------
__global__ __launch_bounds__(1024) void k_scatter(const float* __restrict__ inp,
                                                  const float* __restrict__ grid,
                                                  float4* __restrict__ binned,
                                                  unsigned* __restrict__ cur,
                                                  float* __restrict__ out, int n) {
    __shared__ unsigned cnt[NB];
    __shared__ unsigned base[NB];
    int t = threadIdx.x;
    int P = n >> 1;
    int stride = gridDim.x * 1024;
    int iters = (P + stride - 1) / stride;

    if ((n & 1) && blockIdx.x == 0 && t == 0) {
        int i = n - 1;
        float px = inp[3 * i], py = inp[3 * i + 1], pz = inp[3 * i + 2];
        int b = fine_bin3(px, py, pz);
        unsigned r = atomicAdd(&cur[b], 1u);
        if (r - (unsigned)b * CAP < CAP) {
            float4 v; v.x = px; v.y = py; v.z = pz; v.w = __uint_as_float((unsigned)i);
            binned[r] = v;
        } else {
            int xl, yl, zl; float tx, ty, tz;
            cell_of(px, xl, tx); cell_of(py, yl, ty); cell_of(pz, zl, tz);
            direct_lerp(grid, out, i, xl, yl, zl, tx, ty, tz);
        }
    }

    for (int it = 0; it < iters; ++it) {
        int pr = it * stride + blockIdx.x * 1024 + t;
        for (int k = t; k < NB; k += 1024) cnt[k] = 0;
        __syncthreads();
        int b0 = 0, b1 = 0; unsigned r0 = 0, r1 = 0;
        float4 p0, p1;
        bool valid = (pr < P);
        if (valid) {
            f4v a = *(const f4u*)(inp + 6 * pr);
            f2v b = *(const f2u*)(inp + 6 * pr + 4);
            p0.x = a.x; p0.y = a.y; p0.z = a.z;
            p0.w = __uint_as_float((unsigned)(2 * pr));
            p1.x = a.w; p1.y = b.x; p1.z = b.y;
            p1.w = __uint_as_float((unsigned)(2 * pr + 1));
            b0 = fine_bin3(p0.x, p0.y, p0.z);
            b1 = fine_bin3(p1.x, p1.y, p1.z);
            r0 = atomicAdd(&cnt[b0], 1u);
            r1 = atomicAdd(&cnt[b1], 1u);
        }
        __syncthreads();
        for (int k = t; k < NB; k += 1024)
            if (cnt[k]) base[k] = atomicAdd(&cur[k], cnt[k]);
        __syncthreads();
        if (valid) {
            unsigned s0 = base[b0] + r0;
            unsigned s1 = base[b1] + r1;
            if (s0 - (unsigned)b0 * CAP < CAP) binned[s0] = p0;
            else {
                int xl, yl, zl; float tx, ty, tz;
                cell_of(p0.x, xl, tx); cell_of(p0.y, yl, ty); cell_of(p0.z, zl, tz);
                direct_lerp(grid, out, 2 * pr, xl, yl, zl, tx, ty, tz);
            }
            if (s1 - (unsigned)b1 * CAP < CAP) binned[s1] = p1;
            else {
                int xl, yl, zl; float tx, ty, tz;
                cell_of(p1.x, xl, tx); cell_of(p1.y, yl, ty); cell_of(p1.z, zl, tz);
                direct_lerp(grid, out, 2 * pr + 1, xl, yl, zl, tx, ty, tz);
            }
        }
        __syncthreads();
    }
}

// ---------------- pass 2: z-walk gather, reg-staged, res-coalesced ----------------
#define LOADL(L)                                                        \
    do {                                                                \
        int zg = z0 + (L); if (zg > 255) zg = 255;                      \
        size_t b4 = (size_t)zg * 49152 + (size_t)y0 * 192;              \
        size_t u0 = b4 + (size_t)t;                                     \
        if (u0 > (size_t)(GRIDF4 - 1)) u0 = (size_t)(GRIDF4 - 1);       \
        R0 = *(const f4u*)(grid + u0 * 4);                              \
        if (t < LAYERF4 - 1024) {                                       \
            size_t u1 = b4 + 1024 + (size_t)t;                          \
            if (u1 > (size_t)(GRIDF4 - 1)) u1 = (size_t)(GRIDF4 - 1);   \
            R1 = *(const f4u*)(grid + u1 * 4);                          \
        }                                                               \
    } while (0)

#define WRITEL(slot_)                                                   \
    do {                                                                \
        float* dst = &slab[(slot_) * LAYERF];                           \
        *(f4v*)&dst[(size_t)t * 4] = R0;                                \
        if (t < LAYERF4 - 1024) *(f4v*)&dst[(size_t)(t + 1024) * 4] = R1; \
    } while (0)

__global__ __launch_bounds__(GBLK) void k_gather(const float4* __restrict__ binned,
                                                 const float* __restrict__ grid,
                                                 const unsigned* __restrict__ cur,
                                                 float4* __restrict__ res) {
    __shared__ __align__(16) float slab[3 * LAYERF];   // 82944 B
    int t = threadIdx.x;
    int bin = ((blockIdx.x & 7) << 6) | (blockIdx.x >> 3);   // bijective [0,512)
    int zb = bin >> 5;
    int yb = bin & 31;
    int z0 = zb << 4;
    int y0 = yb << 3;

    f4v R0, R1;

    LOADL(0); WRITEL(0);
    LOADL(1); WRITEL(1);
    LOADL(2);
    __syncthreads();

    for (int zc = 0; zc < 16; ++zc) {
        int sA = (zc % 3) * LAYERF;
        int sB = ((zc + 1) % 3) * LAYERF;

        int K = ((z0 + zc) << 5) | yb;
        unsigned start = (unsigned)K * CAP;
        unsigned count = cur[K] - start;
        if (count > CAP) count = CAP;

        for (unsigned p = (unsigned)t; p < count; p += (unsigned)GBLK) {
            float4 v = binned[start + p];
            unsigned idx = __float_as_uint(v.w);

            int xl, yl, zl; float tx, ty, tz;
            cell_of(v.x, xl, tx);
            cell_of(v.y, yl, ty);
            cell_of(v.z, zl, tz);
            int row = yl - y0;

            int o00 = sA + row * 768 + xl * 3;
            int o01 = o00 + 768;
            int o10 = sB + row * 768 + xl * 3;
            int o11 = o10 + 768;

#define SEG_READ(b, s)                                   \
            do {                                         \
                int e_ = (b) & ~1;                       \
                bool d_ = ((b) & 1) != 0;                \
                f2v q0 = *(const f2u*)(&slab[e_]);       \
                f2v q1 = *(const f2u*)(&slab[e_ + 2]);   \
                f2v q2 = *(const f2u*)(&slab[e_ + 4]);   \
                f2v q3 = *(const f2u*)(&slab[e_ + 6]);   \
                s[0] = d_ ? q0.y : q0.x;                 \
                s[1] = d_ ? q1.x : q0.y;                 \
                s[2] = d_ ? q1.y : q1.x;                 \
                s[3] = d_ ? q2.x : q1.y;                 \
                s[4] = d_ ? q2.y : q2.x;                 \
                s[5] = d_ ? q3.x : q2.y;                 \
            } while (0)

            float s00[6], s01[6], s10[6], s11[6];
            SEG_READ(o00, s00);
            SEG_READ(o01, s01);
            SEG_READ(o10, s10);
            SEG_READ(o11, s11);
#undef SEG_READ

            float o[3];
#pragma unroll
            for (int c = 0; c < 3; ++c) {
                float c00 = s00[c] * (1.0f - tx) + s00[c + 3] * tx;
                float c01 = s01[c] * (1.0f - tx) + s01[c + 3] * tx;
                float c10 = s10[c] * (1.0f - tx) + s10[c + 3] * tx;
                float c11 = s11[c] * (1.0f - tx) + s11[c + 3] * tx;
                float c0 = c00 * (1.0f - ty) + c01 * ty;
                float c1 = c10 * (1.0f - ty) + c11 * ty;
                o[c] = c0 * (1.0f - tz) + c1 * tz;
            }
            // COALESCED result store (slot-parallel to binned) — completes
            // fast, so the per-step vmcnt drain no longer waits on random
            // out-lines.
            float4 r; r.x = o[0]; r.y = o[1]; r.z = o[2]; r.w = __uint_as_float(idx);
            res[start + p] = r;
        }

        __syncthreads();
        if (zc <= 14) WRITEL((zc + 2) % 3);
        if (zc <= 13) LOADL(zc + 3);
        __syncthreads();
    }
}

// ---------------- pass 3: barrier-free unbin scatter (round-2 structure) ----------------
__global__ __launch_bounds__(256) void k_unbin(const float4* __restrict__ res,
                                               const unsigned* __restrict__ cur,
                                               float* __restrict__ out) {
    int bin = blockIdx.x;
    unsigned start = (unsigned)bin * CAP;
    unsigned count = cur[bin] - start;
    if (count > CAP) count = CAP;
    for (unsigned p = (unsigned)threadIdx.x; p < count; p += 256u) {
        float4 r = res[start + p];
        unsigned idx = __float_as_uint(r.w);
        float3 w; w.x = r.x; w.y = r.y; w.z = r.z;
        *(float3*)(out + 3 * (size_t)idx) = w;
    }
}

// ---------------- fallback: direct ----------------
__global__ __launch_bounds__(256) void k_direct(const float* __restrict__ inp,
                                                const float* __restrict__ grid,
                                                float* __restrict__ out, int n) {
    int i = blockIdx.x * blockDim.x + threadIdx.x;
    if (i >= n) return;
    int xl, yl, zl; float tx, ty, tz;
    cell_of(inp[3 * i + 0], xl, tx);
    cell_of(inp[3 * i + 1], yl, ty);
    cell_of(inp[3 * i + 2], zl, tz);
    direct_lerp(grid, out, i, xl, yl, zl, tx, ty, tz);
}

extern "C" void kernel_launch(void* const* d_in, const int* in_sizes, int n_in,
                              void* d_out, int out_size, void* d_ws, size_t ws_size,
                              hipStream_t stream) {
    const float* inp  = (const float*)d_in[0];  // [N][3]
    const float* grid = (const float*)d_in[1];  // [256][256][256][3]
    float* out = (float*)d_out;                 // [N][3]
    int n = in_sizes[0] / 3;

    if (ws_size < (size_t)NEEDED) {
        int blocks = (n + 255) / 256;
        k_direct<<<blocks, 256, 0, stream>>>(inp, grid, out, n);
        return;
    }

    char* ws = (char*)d_ws;
    float4*   binned = (float4*)ws;
    float4*   res    = (float4*)(ws + RES_OFF);
    unsigned* cur    = (unsigned*)(ws + CUR_OFF);

    k_init   <<<8,   1024, 0, stream>>>(cur);
    k_scatter<<<512, 1024, 0, stream>>>(inp, grid, binned, cur, out, n);
    k_gather <<<512, GBLK, 0, stream>>>(binned, grid, cur, res);
    k_unbin  <<<NB,  256,  0, stream>>>(res, cur, out);
}

// Round 19
// 129.505 us; speedup vs baseline: 1.1888x; 1.1888x over previous
//
#include <hip/hip_runtime.h>

// Trilinear feature-grid interpolation, v14: v12 + 2-slot window, 2 blocks/CU.
// grid layout: [R][R][R][3] = [z][y][x][c], R=256, fp32 (192 MB).
//
// v12 (133.4us, best): reg-staged 3-slot rolling window, 83KB LDS -> only
// ONE resident block/CU -> every barrier is a whole-CU bubble. v13's
// store-eviction test failed (+20us) -> reverted. v14: the reg-prefetch
// pipeline needs only 2 LDS slots (trailing barrier already fences
// write-after-read), so window = 55.3KB -> TWO resident 512-thread blocks
// per CU; each block's stage-wait/drain hides under the other's compute.

#define NB     8192
#define CAP    512u
#define GBLK   512
#define LAYERF4 1728              // float4 per layer (9 rows x 192 f4, contiguous)
#define LAYERF  6912              // floats per layer (27648 B)
#define GRIDF4  12582912          // total float4 in grid

// ws layout: binned[8192*512] float4 = 64MB, then cur[8192]
#define CUR_OFF   67108864u
#define NEEDED    (67108864u + 32768u)

typedef float f4v __attribute__((ext_vector_type(4)));
typedef float f2v __attribute__((ext_vector_type(2)));
typedef f4v f4u __attribute__((aligned(8)));
typedef f2v f2u __attribute__((aligned(8)));

__device__ __forceinline__ void cell_of(float p, int& l, float& t) {
    float s = p * 255.0f;
    int v = (int)floorf(s);
    v = v < 0 ? 0 : (v > 254 ? 254 : v);
    l = v;
    t = s - (float)v;
}

// fine bin: K = zl*32 + (yl>>3)  (full x, 8 y-cells, 1 z-cell)
__device__ __forceinline__ int fine_bin3(float px, float py, float pz) {
    int xl, yl, zl; float tx, ty, tz;
    cell_of(px, xl, tx);
    cell_of(py, yl, ty);
    cell_of(pz, zl, tz);
    return (zl << 5) | (yl >> 3);
}

__device__ __forceinline__ void direct_lerp(const float* __restrict__ grid,
                                            float* __restrict__ out, int i,
                                            int xl, int yl, int zl,
                                            float tx, float ty, float tz) {
    int b00 = (zl * 65536 + yl * 256 + xl) * 3;
    int b01 = b00 + 768, b10 = b00 + 196608, b11 = b10 + 768;
    float s00[6], s01[6], s10[6], s11[6];
#pragma unroll
    for (int k = 0; k < 6; ++k) s00[k] = grid[b00 + k];
#pragma unroll
    for (int k = 0; k < 6; ++k) s01[k] = grid[b01 + k];
#pragma unroll
    for (int k = 0; k < 6; ++k) s10[k] = grid[b10 + k];
#pragma unroll
    for (int k = 0; k < 6; ++k) s11[k] = grid[b11 + k];
#pragma unroll
    for (int c = 0; c < 3; ++c) {
        float c00 = s00[c] * (1.0f - tx) + s00[c + 3] * tx;
        float c01 = s01[c] * (1.0f - tx) + s01[c + 3] * tx;
        float c10 = s10[c] * (1.0f - tx) + s10[c + 3] * tx;
        float c11 = s11[c] * (1.0f - tx) + s11[c + 3] * tx;
        float c0 = c00 * (1.0f - ty) + c01 * ty;
        float c1 = c10 * (1.0f - ty) + c11 * ty;
        out[3 * i + c] = c0 * (1.0f - tz) + c1 * tz;
    }
}

// ---------------- pass 0: init cursors to region bases ----------------
__global__ __launch_bounds__(1024) void k_init(unsigned* __restrict__ cur) {
    int i = blockIdx.x * 1024 + threadIdx.x;
    if (i < NB) cur[i] = (unsigned)i * CAP;
}

// ---------------- pass 1: block-aggregated scatter (2 pts/thread) ----------------
__global__ __launch_bounds__(1024) void k_scatter(const float* __restrict__ inp,
                                                  const float* __restrict__ grid,
                                                  float4* __restrict__ binned,
                                                  unsigned* __restrict__ cur,
                                                  float* __restrict__ out, int n) {
    __shared__ unsigned cnt[NB];
    __shared__ unsigned base[NB];
    int t = threadIdx.x;
    int P = n >> 1;
    int stride = gridDim.x * 1024;
    int iters = (P + stride - 1) / stride;

    if ((n & 1) && blockIdx.x == 0 && t == 0) {
        int i = n - 1;
        float px = inp[3 * i], py = inp[3 * i + 1], pz = inp[3 * i + 2];
        int b = fine_bin3(px, py, pz);
        unsigned r = atomicAdd(&cur[b], 1u);
        if (r - (unsigned)b * CAP < CAP) {
            float4 v; v.x = px; v.y = py; v.z = pz; v.w = __uint_as_float((unsigned)i);
            binned[r] = v;
        } else {
            int xl, yl, zl; float tx, ty, tz;
            cell_of(px, xl, tx); cell_of(py, yl, ty); cell_of(pz, zl, tz);
            direct_lerp(grid, out, i, xl, yl, zl, tx, ty, tz);
        }
    }

    for (int it = 0; it < iters; ++it) {
        int pr = it * stride + blockIdx.x * 1024 + t;
        for (int k = t; k < NB; k += 1024) cnt[k] = 0;
        __syncthreads();
        int b0 = 0, b1 = 0; unsigned r0 = 0, r1 = 0;
        float4 p0, p1;
        bool valid = (pr < P);
        if (valid) {
            f4v a = *(const f4u*)(inp + 6 * pr);
            f2v b = *(const f2u*)(inp + 6 * pr + 4);
            p0.x = a.x; p0.y = a.y; p0.z = a.z;
            p0.w = __uint_as_float((unsigned)(2 * pr));
            p1.x = a.w; p1.y = b.x; p1.z = b.y;
            p1.w = __uint_as_float((unsigned)(2 * pr + 1));
            b0 = fine_bin3(p0.x, p0.y, p0.z);
            b1 = fine_bin3(p1.x, p1.y, p1.z);
            r0 = atomicAdd(&cnt[b0], 1u);
            r1 = atomicAdd(&cnt[b1], 1u);
        }
        __syncthreads();
        for (int k = t; k < NB; k += 1024)
            if (cnt[k]) base[k] = atomicAdd(&cur[k], cnt[k]);
        __syncthreads();
        if (valid) {
            unsigned s0 = base[b0] + r0;
            unsigned s1 = base[b1] + r1;
            if (s0 - (unsigned)b0 * CAP < CAP) binned[s0] = p0;
            else {
                int xl, yl, zl; float tx, ty, tz;
                cell_of(p0.x, xl, tx); cell_of(p0.y, yl, ty); cell_of(p0.z, zl, tz);
                direct_lerp(grid, out, 2 * pr, xl, yl, zl, tx, ty, tz);
            }
            if (s1 - (unsigned)b1 * CAP < CAP) binned[s1] = p1;
            else {
                int xl, yl, zl; float tx, ty, tz;
                cell_of(p1.x, xl, tx); cell_of(p1.y, yl, ty); cell_of(p1.z, zl, tz);
                direct_lerp(grid, out, 2 * pr + 1, xl, yl, zl, tx, ty, tz);
            }
        }
        __syncthreads();
    }
}

// ---------------- pass 2: z-walk gather, reg-staged 2-slot window ----------------
// Layer L of this block = grid[z0+L][y0..y0+9)][*] : 1728 contiguous float4.
// 512 threads: thread t covers f4 indices t, t+512, t+1024, (t<192: t+1536).
#define LOADL(L)                                                        \
    do {                                                                \
        int zg = z0 + (L); if (zg > 255) zg = 255;                      \
        size_t b4 = (size_t)zg * 49152 + (size_t)y0 * 192;              \
        size_t u0 = b4 + (size_t)t;                                     \
        size_t u1 = b4 + 512 + (size_t)t;                               \
        size_t u2 = b4 + 1024 + (size_t)t;                              \
        if (u0 > (size_t)(GRIDF4 - 1)) u0 = (size_t)(GRIDF4 - 1);       \
        if (u1 > (size_t)(GRIDF4 - 1)) u1 = (size_t)(GRIDF4 - 1);       \
        if (u2 > (size_t)(GRIDF4 - 1)) u2 = (size_t)(GRIDF4 - 1);       \
        R0 = *(const f4u*)(grid + u0 * 4);                              \
        R1 = *(const f4u*)(grid + u1 * 4);                              \
        R2 = *(const f4u*)(grid + u2 * 4);                              \
        if (t < LAYERF4 - 1536) {                                       \
            size_t u3 = b4 + 1536 + (size_t)t;                          \
            if (u3 > (size_t)(GRIDF4 - 1)) u3 = (size_t)(GRIDF4 - 1);   \
            R3 = *(const f4u*)(grid + u3 * 4);                          \
        }                                                               \
    } while (0)

#define WRITEL(slot_)                                                   \
    do {                                                                \
        float* dst = &slab[(slot_) * LAYERF];                           \
        *(f4v*)&dst[(size_t)t * 4] = R0;                                \
        *(f4v*)&dst[(size_t)(t + 512) * 4] = R1;                        \
        *(f4v*)&dst[(size_t)(t + 1024) * 4] = R2;                       \
        if (t < LAYERF4 - 1536) *(f4v*)&dst[(size_t)(t + 1536) * 4] = R3; \
    } while (0)

__global__ __launch_bounds__(GBLK) void k_gather(const float4* __restrict__ binned,
                                                 const float* __restrict__ grid,
                                                 const unsigned* __restrict__ cur,
                                                 float* __restrict__ out) {
    __shared__ __align__(16) float slab[2 * LAYERF];   // 55296 B -> 2 blocks/CU
    int t = threadIdx.x;
    // 512 blocks; XCD-chunked: XCD k owns bins [64k, 64k+64) = 2 contiguous
    // z-segments x all y (halo layers shared within the XCD's L2).
    int bin = ((blockIdx.x & 7) << 6) | (blockIdx.x >> 3);   // bijective [0,512)
    int zb = bin >> 5;            // 16 z-segments of 16 cells
    int yb = bin & 31;            // 32 y-bins of 8 cells
    int z0 = zb << 4;
    int y0 = yb << 3;

    f4v R0, R1, R2, R3;

    LOADL(0); WRITEL(0);          // layer 0 -> slot 0 (ds_write waits vmcnt)
    LOADL(1);                     // layer 1 in regs

    for (int zc = 0; zc < 16; ++zc) {
        // Write layer zc+1 (in regs) into slot (zc+1)&1. Previous content
        // (layer zc-1) was last read at step zc-1, fenced by its trailing
        // barrier. Compiler inserts the vmcnt wait for the LOADL regs.
        WRITEL((zc + 1) & 1);
        __syncthreads();          // ds_writes visible to all waves

        // Issue layer zc+2's loads; they fly under this step's compute and
        // must land before next step's WRITEL. zc<=14 stages z0+16 (upper
        // layer of step 15) — the round-15 bug class, guard re-audited.
        if (zc <= 14) LOADL(zc + 2);

        int sA = (zc & 1) * LAYERF;
        int sB = ((zc + 1) & 1) * LAYERF;

        int K = ((z0 + zc) << 5) | yb;
        unsigned start = (unsigned)K * CAP;
        unsigned count = cur[K] - start;
        if (count > CAP) count = CAP;

        for (unsigned p = (unsigned)t; p < count; p += (unsigned)GBLK) {
            float4 v = binned[start + p];
            unsigned idx = __float_as_uint(v.w);

            int xl, yl, zl; float tx, ty, tz;
            cell_of(v.x, xl, tx);
            cell_of(v.y, yl, ty);
            cell_of(v.z, zl, tz);
            int row = yl - y0;                 // 0..7

            int o00 = sA + row * 768 + xl * 3;
            int o01 = o00 + 768;
            int o10 = sB + row * 768 + xl * 3;
            int o11 = o10 + 768;

#define SEG_READ(b, s)                                   \
            do {                                         \
                int e_ = (b) & ~1;                       \
                bool d_ = ((b) & 1) != 0;                \
                f2v q0 = *(const f2u*)(&slab[e_]);       \
                f2v q1 = *(const f2u*)(&slab[e_ + 2]);   \
                f2v q2 = *(const f2u*)(&slab[e_ + 4]);   \
                f2v q3 = *(const f2u*)(&slab[e_ + 6]);   \
                s[0] = d_ ? q0.y : q0.x;                 \
                s[1] = d_ ? q1.x : q0.y;                 \
                s[2] = d_ ? q1.y : q1.x;                 \
                s[3] = d_ ? q2.x : q1.y;                 \
                s[4] = d_ ? q2.y : q2.x;                 \
                s[5] = d_ ? q3.x : q2.y;                 \
            } while (0)

            float s00[6], s01[6], s10[6], s11[6];
            SEG_READ(o00, s00);   // (zl,   yl)
            SEG_READ(o01, s01);   // (zl,   yl+1)
            SEG_READ(o10, s10);   // (zl+1, yl)
            SEG_READ(o11, s11);   // (zl+1, yl+1)
#undef SEG_READ

            float o[3];
#pragma unroll
            for (int c = 0; c < 3; ++c) {
                float c00 = s00[c] * (1.0f - tx) + s00[c + 3] * tx;
                float c01 = s01[c] * (1.0f - tx) + s01[c + 3] * tx;
                float c10 = s10[c] * (1.0f - tx) + s10[c + 3] * tx;
                float c11 = s11[c] * (1.0f - tx) + s11[c + 3] * tx;
                float c0 = c00 * (1.0f - ty) + c01 * ty;
                float c1 = c10 * (1.0f - ty) + c11 * ty;
                o[c] = c0 * (1.0f - tz) + c1 * tz;
            }
            float3 w; w.x = o[0]; w.y = o[1]; w.z = o[2];
            *(float3*)(out + 3 * (size_t)idx) = w;
        }

        // Fence this step's slab readers before next step's WRITEL overwrites
        // slot zc&1.
        __syncthreads();
    }
}

// ---------------- fallback: direct ----------------
__global__ __launch_bounds__(256) void k_direct(const float* __restrict__ inp,
                                                const float* __restrict__ grid,
                                                float* __restrict__ out, int n) {
    int i = blockIdx.x * blockDim.x + threadIdx.x;
    if (i >= n) return;
    int xl, yl, zl; float tx, ty, tz;
    cell_of(inp[3 * i + 0], xl, tx);
    cell_of(inp[3 * i + 1], yl, ty);
    cell_of(inp[3 * i + 2], zl, tz);
    direct_lerp(grid, out, i, xl, yl, zl, tx, ty, tz);
}

extern "C" void kernel_launch(void* const* d_in, const int* in_sizes, int n_in,
                              void* d_out, int out_size, void* d_ws, size_t ws_size,
                              hipStream_t stream) {
    const float* inp  = (const float*)d_in[0];  // [N][3]
    const float* grid = (const float*)d_in[1];  // [256][256][256][3]
    float* out = (float*)d_out;                 // [N][3]
    int n = in_sizes[0] / 3;

    if (ws_size < (size_t)NEEDED) {
        int blocks = (n + 255) / 256;
        k_direct<<<blocks, 256, 0, stream>>>(inp, grid, out, n);
        return;
    }

    char* ws = (char*)d_ws;
    float4*   binned = (float4*)ws;
    unsigned* cur    = (unsigned*)(ws + CUR_OFF);

    k_init   <<<8,   1024, 0, stream>>>(cur);
    k_scatter<<<512, 1024, 0, stream>>>(inp, grid, binned, cur, out, n);
    k_gather <<<512, GBLK, 0, stream>>>(binned, grid, cur, out);
}